// Round 4
// baseline (149.812 us; speedup 1.0000x reference)
//
#include <hip/hip_runtime.h>
#include <hip/hip_bf16.h>
#include <math.h>

typedef __attribute__((ext_vector_type(8))) short bf16x8;
typedef __attribute__((ext_vector_type(4))) float f32x4;
typedef __attribute__((ext_vector_type(4))) unsigned int u32x4;

#define NSC    8
#define SLEN   4096
#define FEAT   64
#define W_TOT  10368      // padded elems per wavelet copy (sum of round8(L+160))
#define W_TOT2 22528      // 2 copies + tail pad -> 45056 bytes (11 * 4096)

struct WavP  { int off[NSC]; int L[NSC]; float step[NSC]; float isq[NSC]; };
struct MainP { int cact[NSC]; int baseS[NSC]; };

// ---------------- kernel 1: build dilated, reversed, padded wavelets (bf16) ----
// copy0[x] = Rv(x), copy1[x] = Rv(x+1), where Rv(x) = w~[L+96-x] for 97<=x<=L+96 else 0.
// w~(k) = interp(mother, k*step) * (1/sqrt(scale)) * scale_weight   (matches jnp.interp)
__global__ void k_build_wav(const float* __restrict__ mw, const float* __restrict__ sw,
                            __hip_bfloat16* __restrict__ wg, WavP wp)
{
  for (int e = blockIdx.x * 256 + threadIdx.x; e < W_TOT2; e += gridDim.x * 256) {
    float val = 0.f;
    int p = 0, e2 = e;
    if (e2 >= W_TOT) { p = 1; e2 -= W_TOT; }
    if (e2 < W_TOT) {
      int s = 0;
      #pragma unroll
      for (int i = 1; i < NSC; ++i) if (e2 >= wp.off[i]) s = i;
      int x = e2 - wp.off[s] + p;
      int L = wp.L[s];
      if (x >= 97 && x <= L + 96) {
        int k = L + 96 - x;
        float pos = (float)k * wp.step[s];
        int ii = (int)pos;
        float r;
        if (ii >= 63) r = mw[s * 64 + 63];
        else {
          float a = mw[s * 64 + ii];
          r = fmaf(pos - (float)ii, mw[s * 64 + ii + 1] - a, a);
        }
        val = r * wp.isq[s] * sw[s];
      }
    }
    wg[e] = __float2bfloat16(val);
  }
}

// ---------------- kernel 2: signal f32 [b][r][f] -> bf16 [b][rblk][f][64] -------
__global__ __launch_bounds__(256) void k_transpose(const float* __restrict__ sig,
                                                   __hip_bfloat16* __restrict__ sigT2)
{
  __shared__ float t[64][65];
  const int tid = threadIdx.x;
  const float* sp = sig + (size_t)blockIdx.x * 4096;          // (b*64+rblk)*64*64
  for (int idx = tid; idx < 4096; idx += 256)
    t[idx & 63][idx >> 6] = sp[idx];                          // t[f][r]
  __syncthreads();
  __hip_bfloat16* op = sigT2 + (size_t)blockIdx.x * 4096;
  for (int idx = tid; idx < 4096; idx += 256)
    op[idx] = __float2bfloat16(t[idx >> 6][idx & 63]);        // [f][r]
}

// ---------------- kernel 3: banded-Toeplitz MFMA convolution --------------------
// Block = 256 thr = 4 waves; block owns (b, 64-t tile); wave tw owns rows t0+16tw..+15.
// LDS holds ONLY the wavelet table (A); B-fragments stream from global (L1/L2)
// via per-lane global_load_dwordx4, software-pipelined one k-step ahead.
// No __syncthreads in the main loop.
__global__ __launch_bounds__(256, 2) void k_wavelet_mfma(
    const __hip_bfloat16* __restrict__ sigT2,
    const __hip_bfloat16* __restrict__ wavg,
    float* __restrict__ out, MainP P)
{
  __shared__ __align__(16) short ldsW[W_TOT2];

  const int tid = threadIdx.x;
  const int bid = blockIdx.x;
  const int tt  = 63 - (bid >> 4);        // heavy (large t0) tiles first
  const int b   = bid & 15;
  const int t0  = tt * 64;
  const int tw  = tid >> 6;               // wave id
  const int fl  = tid & 15;               // lane&15: A-row / B-col / D-col
  const int g   = (tid >> 4) & 3;         // lane>>4: k-group / D-row-group
  const int lanepart = 8 * g - fl;

  // stage wavelets (45056 B) into LDS once, 16B per lane per issue
  {
    const char* gp = (const char*)wavg;
    char* lp = (char*)ldsW;
    #pragma unroll
    for (int it = 0; it < 11; ++it)
      __builtin_amdgcn_global_load_lds(
        (const __attribute__((address_space(1))) void*)(gp + it * 4096 + tid * 16),
        (__attribute__((address_space(3))) void*)(lp + it * 4096 + (tid >> 6) * 1024),
        16, 0, 0);
  }
  __syncthreads();                        // only barrier in the kernel

  const int C = tt + 1;                   // 64-row groups: rows [64(tt-c), +63]
  // per-lane B base: element (b*64+tt)*4096 + fl*64 + g*8 ; (c,h,n) adds -c*4096 + n*1024 + h*32
  const __hip_bfloat16* sgb = sigT2 + ((size_t)(b * 64 + tt) << 12) + (fl << 6) + (g << 3);

  f32x4 acc[NSC][4];
  const f32x4 z = {0.f, 0.f, 0.f, 0.f};
  #pragma unroll
  for (int s = 0; s < NSC; ++s)
    #pragma unroll
    for (int n = 0; n < 4; ++n) acc[s][n] = z;

  auto compute = [&](int c_old, const bf16x8* Bf) {
    const int wk = 32 - 16 * tw - 32 * c_old + lanepart;
    __builtin_amdgcn_s_setprio(1);
    #pragma unroll
    for (int s = NSC - 1; s >= 0; --s) {
      if (c_old <= P.cact[s]) {           // wave-uniform; static acc indices
        int yb  = P.baseS[s] + wk;        // element index into copy0
        int pr  = yb & 1;                 // odd -> use shifted copy1
        int idx = yb - pr + pr * W_TOT;
        const unsigned int* ap = (const unsigned int*)(ldsW + idx);
        u32x4 au;
        au.x = ap[0]; au.y = ap[1]; au.z = ap[2]; au.w = ap[3];
        bf16x8 Af = __builtin_bit_cast(bf16x8, au);
        acc[s][0] = __builtin_amdgcn_mfma_f32_16x16x32_bf16(Af, Bf[0], acc[s][0], 0, 0, 0);
        acc[s][1] = __builtin_amdgcn_mfma_f32_16x16x32_bf16(Af, Bf[1], acc[s][1], 0, 0, 0);
        acc[s][2] = __builtin_amdgcn_mfma_f32_16x16x32_bf16(Af, Bf[2], acc[s][2], 0, 0, 0);
        acc[s][3] = __builtin_amdgcn_mfma_f32_16x16x32_bf16(Af, Bf[3], acc[s][3], 0, 0, 0);
      }
    }
    __builtin_amdgcn_s_setprio(0);
  };

  bf16x8 B0[4], B1[4];
  #pragma unroll
  for (int n = 0; n < 4; ++n)             // prologue: (c=0, h=1)
    B0[n] = *(const bf16x8*)(sgb + n * 1024 + 32);

  for (int c = 0; c < C; ++c) {
    // prefetch (c, h=0) into B1, compute (c, h=1) from B0  [c_old = 2c]
    #pragma unroll
    for (int n = 0; n < 4; ++n)
      B1[n] = *(const bf16x8*)(sgb - c * 4096 + n * 1024);
    compute(2 * c, B0);
    // prefetch (c+1, h=1) into B0, compute (c, h=0) from B1  [c_old = 2c+1]
    // (last prefetch dangles one chunk below rblk 0 -> still inside d_ws, unused)
    #pragma unroll
    for (int n = 0; n < 4; ++n)
      B0[n] = *(const bf16x8*)(sgb - (c + 1) * 4096 + n * 1024 + 32);
    compute(2 * c + 1, B1);
  }

  // epilogue: D row = 4*g + reg, col = 16n + fl
  const int trow = t0 + tw * 16 + g * 4;
  float* ob = out + (size_t)b * NSC * SLEN * FEAT;
  #pragma unroll
  for (int s = 0; s < NSC; ++s) {
    float* os = ob + (size_t)s * SLEN * FEAT;
    #pragma unroll
    for (int n = 0; n < 4; ++n)
      #pragma unroll
      for (int r = 0; r < 4; ++r)
        os[(size_t)(trow + r) * FEAT + n * 16 + fl] = acc[s][n][r];
  }
}

extern "C" void kernel_launch(void* const* d_in, const int* in_sizes, int n_in,
                              void* d_out, int out_size, void* d_ws, size_t ws_size,
                              hipStream_t stream) {
  const float* sig = (const float*)d_in[0];
  const float* mw  = (const float*)d_in[1];
  const float* sw  = (const float*)d_in[2];
  float*       out = (float*)d_out;

  // workspace layout: [0,45056+slack) wavelets bf16; [65536, +8388608) sigT2 bf16
  __hip_bfloat16* wavg  = (__hip_bfloat16*)d_ws;
  __hip_bfloat16* sigT2 = (__hip_bfloat16*)((char*)d_ws + 65536);

  // host precompute: np.logspace(0, log10(64), 8), L = int(64*scale) (truncation)
  WavP wp; MainP mp;
  const double lg = log10(64.0), st = lg / 7.0;
  int off = 0;
  for (int i = 0; i < NSC; ++i) {
    double y = (i == 7) ? lg : (double)i * st;
    double s = pow(10.0, y);
    int L = (int)(64.0 * s);
    wp.L[i]    = L;
    wp.step[i] = (float)(63.0 / (double)(L - 1));
    wp.isq[i]  = (float)(1.0 / sqrt(s));
    wp.off[i]  = off;
    mp.cact[i]  = (L + 62) >> 5;          // last active 32-row k-step index
    mp.baseS[i] = off + L + 96;           // off_s + K0_s
    off += ((L + 160 + 7) / 8) * 8;       // round8(L+160), sums to W_TOT=10368
  }

  k_build_wav<<<64, 256, 0, stream>>>(mw, sw, wavg, wp);
  k_transpose<<<1024, 256, 0, stream>>>(sig, sigT2);
  k_wavelet_mfma<<<1024, 256, 0, stream>>>(sigT2, wavg, out, mp);
}

// Round 5
// 80.614 us; speedup vs baseline: 1.8584x; 1.8584x over previous
//
#include <hip/hip_runtime.h>
#include <hip/hip_bf16.h>
#include <math.h>

typedef __attribute__((ext_vector_type(8))) short bf16x8;
typedef __attribute__((ext_vector_type(4))) float f32x4;
typedef __attribute__((ext_vector_type(4))) unsigned int u32x4;

#define NSC    8
#define SLEN   4096
#define FEAT   64
#define W_TOT  10368      // padded elems per wavelet copy (sum of round8(L+160))
#define W_TOT2 22528      // 2 copies + tail pad -> 45056 bytes (11 * 4096)
#define CHUNK_B 8192      // one 64-row chunk of sigT2, bytes

struct WavP  { int off[NSC]; int L[NSC]; float step[NSC]; float isq[NSC]; };
struct MainP { int cact[NSC]; int baseS[NSC]; };

// ---------------- kernel 1: build dilated, reversed, padded wavelets (bf16) ----
// copy0[x] = Rv(x), copy1[x] = Rv(x+1), where Rv(x) = w~[L+96-x] for 97<=x<=L+96 else 0.
// w~(k) = interp(mother, k*step) * (1/sqrt(scale)) * scale_weight   (matches jnp.interp)
__global__ void k_build_wav(const float* __restrict__ mw, const float* __restrict__ sw,
                            __hip_bfloat16* __restrict__ wg, WavP wp)
{
  for (int e = blockIdx.x * 256 + threadIdx.x; e < W_TOT2; e += gridDim.x * 256) {
    float val = 0.f;
    int p = 0, e2 = e;
    if (e2 >= W_TOT) { p = 1; e2 -= W_TOT; }
    if (e2 < W_TOT) {
      int s = 0;
      #pragma unroll
      for (int i = 1; i < NSC; ++i) if (e2 >= wp.off[i]) s = i;
      int x = e2 - wp.off[s] + p;
      int L = wp.L[s];
      if (x >= 97 && x <= L + 96) {
        int k = L + 96 - x;
        float pos = (float)k * wp.step[s];
        int ii = (int)pos;
        float r;
        if (ii >= 63) r = mw[s * 64 + 63];
        else {
          float a = mw[s * 64 + ii];
          r = fmaf(pos - (float)ii, mw[s * 64 + ii + 1] - a, a);
        }
        val = r * wp.isq[s] * sw[s];
      }
    }
    wg[e] = __float2bfloat16(val);
  }
}

// ---------------- kernel 2: signal f32 [b][r][f] -> bf16 FRAGMENT-ORDERED -------
// Per 64-row chunk (b*64+rb): element index e = h*2048 + n*512 + l*8 + i holds
// sig[r = rb*64 + h*32 + (l>>4)*8 + i][f = n*16 + (l&15)].
// So the main kernel's B-fragment (c,h,n) is ONE contiguous 1024B wave64 load.
__global__ __launch_bounds__(256) void k_transpose(const float* __restrict__ sig,
                                                   __hip_bfloat16* __restrict__ sigT2)
{
  __shared__ float t[4096];                 // flat [r][f], XOR-swizzled banks
  const int tid = threadIdx.x;
  const float* sp = sig + (size_t)blockIdx.x * 4096;          // chunk (b*64+rb)
  for (int idx = tid; idx < 4096; idx += 256) {
    int r = idx >> 6, f = idx & 63;
    t[(r << 6) + (f ^ ((r & 7) << 3))] = sp[idx];
  }
  __syncthreads();
  __hip_bfloat16* op = sigT2 + (size_t)blockIdx.x * 4096;
  for (int e = tid; e < 4096; e += 256) {
    int h = e >> 11, n = (e >> 9) & 3, l = (e >> 3) & 63, i = e & 7;
    int f = n * 16 + (l & 15);
    int r = h * 32 + (l >> 4) * 8 + i;
    op[e] = __float2bfloat16(t[(r << 6) + (f ^ ((r & 7) << 3))]);
  }
}

// ---------------- kernel 3: banded-Toeplitz MFMA convolution --------------------
// Block = 256 thr = 4 waves; block owns (b, 64-t tile); wave tw owns rows t0+16tw..+15.
// LDS: wavelet (A) table only. B streams from global via coalesced 1024B wave loads,
// double-buffered one full chunk (2 k-steps) ahead. No in-loop barriers.
__global__ __launch_bounds__(256, 2) void k_wavelet_mfma(
    const __hip_bfloat16* __restrict__ sigT2,
    const __hip_bfloat16* __restrict__ wavg,
    float* __restrict__ out, MainP P)
{
  __shared__ __align__(16) short ldsW[W_TOT2];

  const int tid = threadIdx.x;
  const int bid = blockIdx.x;
  const int tt  = 63 - (bid >> 4);        // heavy (large t0) tiles first
  const int b   = bid & 15;
  const int t0  = tt * 64;
  const int tw  = tid >> 6;               // wave id
  const int fl  = tid & 15;               // lane&15: A-row / B-col / D-col
  const int g   = (tid >> 4) & 3;         // lane>>4: k-group / D-row-group
  const int lanepart = 8 * g - fl;

  // stage wavelets (45056 B) into LDS once, 16B per lane per issue
  {
    const char* gp = (const char*)wavg;
    char* lp = (char*)ldsW;
    #pragma unroll
    for (int it = 0; it < 11; ++it)
      __builtin_amdgcn_global_load_lds(
        (const __attribute__((address_space(1))) void*)(gp + it * 4096 + tid * 16),
        (__attribute__((address_space(3))) void*)(lp + it * 4096 + (tid >> 6) * 1024),
        16, 0, 0);
  }
  __syncthreads();                        // only barrier in the kernel

  const int C = tt + 1;                   // chunks: rows [64(tt-c), +63], c=0..C-1
  // per-block chunk base; per-lane +l*16 inside each 1024B fragment
  const char* cb = (const char*)sigT2 + ((size_t)(b * 64 + tt)) * CHUNK_B
                   + (size_t)(tid & 63) * 16;

  f32x4 acc[NSC][4];
  const f32x4 z = {0.f, 0.f, 0.f, 0.f};
  #pragma unroll
  for (int s = 0; s < NSC; ++s)
    #pragma unroll
    for (int n = 0; n < 4; ++n) acc[s][n] = z;

  bf16x8 Ba[8], Bb[8];
  // loads may dangle up to 2 chunks below rb=0 -> still >= d_ws base (offset 65536), unused
  auto loadchunk = [&](int c, bf16x8* B) {
    const char* p = cb - (size_t)c * CHUNK_B;
    #pragma unroll
    for (int hn = 0; hn < 8; ++hn)
      B[hn] = *(const bf16x8*)(p + (hn >> 2) * 4096 + (hn & 3) * 1024);
  };

  auto compute = [&](int c_old, const bf16x8* Bf) {
    const int wk = 32 - 16 * tw - 32 * c_old + lanepart;
    __builtin_amdgcn_s_setprio(1);
    #pragma unroll
    for (int s = NSC - 1; s >= 0; --s) {
      if (c_old <= P.cact[s]) {           // wave-uniform; static acc indices
        int yb  = P.baseS[s] + wk;        // element index into copy0
        int pr  = yb & 1;                 // odd -> use shifted copy1
        int idx = yb - pr + pr * W_TOT;
        const unsigned int* ap = (const unsigned int*)(ldsW + idx);
        u32x4 au;
        au.x = ap[0]; au.y = ap[1]; au.z = ap[2]; au.w = ap[3];
        bf16x8 Af = __builtin_bit_cast(bf16x8, au);
        acc[s][0] = __builtin_amdgcn_mfma_f32_16x16x32_bf16(Af, Bf[0], acc[s][0], 0, 0, 0);
        acc[s][1] = __builtin_amdgcn_mfma_f32_16x16x32_bf16(Af, Bf[1], acc[s][1], 0, 0, 0);
        acc[s][2] = __builtin_amdgcn_mfma_f32_16x16x32_bf16(Af, Bf[2], acc[s][2], 0, 0, 0);
        acc[s][3] = __builtin_amdgcn_mfma_f32_16x16x32_bf16(Af, Bf[3], acc[s][3], 0, 0, 0);
      }
    }
    __builtin_amdgcn_s_setprio(0);
  };

  loadchunk(0, Ba);

  for (int c = 0; c < C; c += 2) {
    loadchunk(c + 1, Bb);                 // in flight across Ba's compute
    // chunk c: h=1 (upper 32 rows) is c_old=2c; h=0 is c_old=2c+1
    compute(2 * c,     &Ba[4]);
    compute(2 * c + 1, &Ba[0]);
    loadchunk(c + 2, Ba);                 // in flight across Bb's compute
    if (c + 1 < C) {
      compute(2 * c + 2, &Bb[4]);
      compute(2 * c + 3, &Bb[0]);
    }
  }

  // epilogue: D row = 4*g + reg, col = 16n + fl
  const int trow = t0 + tw * 16 + g * 4;
  float* ob = out + (size_t)b * NSC * SLEN * FEAT;
  #pragma unroll
  for (int s = 0; s < NSC; ++s) {
    float* os = ob + (size_t)s * SLEN * FEAT;
    #pragma unroll
    for (int n = 0; n < 4; ++n)
      #pragma unroll
      for (int r = 0; r < 4; ++r)
        os[(size_t)(trow + r) * FEAT + n * 16 + fl] = acc[s][n][r];
  }
}

extern "C" void kernel_launch(void* const* d_in, const int* in_sizes, int n_in,
                              void* d_out, int out_size, void* d_ws, size_t ws_size,
                              hipStream_t stream) {
  const float* sig = (const float*)d_in[0];
  const float* mw  = (const float*)d_in[1];
  const float* sw  = (const float*)d_in[2];
  float*       out = (float*)d_out;

  // workspace layout: [0,45056+slack) wavelets bf16; [65536, +8388608) sigT2 bf16
  __hip_bfloat16* wavg  = (__hip_bfloat16*)d_ws;
  __hip_bfloat16* sigT2 = (__hip_bfloat16*)((char*)d_ws + 65536);

  // host precompute: np.logspace(0, log10(64), 8), L = int(64*scale) (truncation)
  WavP wp; MainP mp;
  const double lg = log10(64.0), st = lg / 7.0;
  int off = 0;
  for (int i = 0; i < NSC; ++i) {
    double y = (i == 7) ? lg : (double)i * st;
    double s = pow(10.0, y);
    int L = (int)(64.0 * s);
    wp.L[i]    = L;
    wp.step[i] = (float)(63.0 / (double)(L - 1));
    wp.isq[i]  = (float)(1.0 / sqrt(s));
    wp.off[i]  = off;
    mp.cact[i]  = (L + 62) >> 5;          // last active 32-row k-step index
    mp.baseS[i] = off + L + 96;           // off_s + K0_s
    off += ((L + 160 + 7) / 8) * 8;       // round8(L+160), sums to W_TOT=10368
  }

  k_build_wav<<<64, 256, 0, stream>>>(mw, sw, wavg, wp);
  k_transpose<<<1024, 256, 0, stream>>>(sig, sigT2);
  k_wavelet_mfma<<<1024, 256, 0, stream>>>(sigT2, wavg, out, mp);
}